// Round 13
// baseline (156.134 us; speedup 1.0000x reference)
//
#include <hip/hip_runtime.h>
#include <hip/hip_bf16.h>
#include <stdint.h>

// CapsuleLayer dynamic routing v13 = v12 with 4 WG/CU route geometry.
// u_hat per i is a GEMM: U^T[(j,k), b] = W_i[(j,k), l] x^T[l, b] via
// mfma_f32_16x16x32_bf16 (M=16 k's of one j, N=16 b, K=32 with l=8 real,
// zero-padded A). C layout (m89): col=lane&15=b, row=(lane>>4)*4+reg=k.
// v12 ledger: 3x route ~= 88us of 114; route is latency-bound on the
// per-iter softmax barrier at only 2 WG/CU (grid 512). v13: I_TILE 18->9,
// grid 1024 = 4 WG/CU exact (VGPR=64 -> 8 waves/SIMD, LDS 34KB*4 <= 160KB,
// 2048 thr = max). Compute body byte-identical to keep VGPR at 64.
// v11's fused-squash fence storm stays reverted; s-zero lives in prep_x.

using fab = __attribute__((ext_vector_type(8))) short;   // 8 bf16 = 4 VGPR
using fcc = __attribute__((ext_vector_type(4))) float;   // 4 f32 accum

__device__ __forceinline__ uint32_t bfr(float f) {   // fp32 -> bf16 RTN-even
    uint32_t u = __float_as_uint(f);
    return (u + 0x7fffu + ((u >> 16) & 1u)) >> 16;
}

// W3[((i*32 + j)*16 + k)*8 + l] bf16  (16B per (i,j,k) row)
__global__ __launch_bounds__(256)
void prep_w(const float* __restrict__ W, ushort* __restrict__ W3)
{
    const int t = blockIdx.x * 256 + threadIdx.x;   // (i,j,k), k fastest
    const int k = t & 15, j = (t >> 4) & 31, i = t >> 9;
    const float* src = W + (((size_t)j * 1152 + i) * 16 + k) * 8;
    const float4 a = *reinterpret_cast<const float4*>(src);
    const float4 b = *reinterpret_cast<const float4*>(src + 4);
    uint4 o;
    o.x = bfr(a.x) | (bfr(a.y) << 16);
    o.y = bfr(a.z) | (bfr(a.w) << 16);
    o.z = bfr(b.x) | (bfr(b.y) << 16);
    o.w = bfr(b.z) | (bfr(b.w) << 16);
    *reinterpret_cast<uint4*>(W3 + (size_t)t * 8) = o;
}

// x2T[(i*128 + b)*8 + l] bf16 ; also zeroes s (65536 f32)
__global__ __launch_bounds__(256)
void prep_x(const float* __restrict__ x, ushort* __restrict__ X2,
            float4* __restrict__ s4)
{
    const int t = blockIdx.x * 256 + threadIdx.x;   // (i,b), b fastest
    const int b = t & 127, i = t >> 7;
    const float* src = x + ((size_t)b * 1152 + i) * 8;
    const float4 a = *reinterpret_cast<const float4*>(src);
    const float4 bb = *reinterpret_cast<const float4*>(src + 4);
    uint4 o;
    o.x = bfr(a.x) | (bfr(a.y) << 16);
    o.y = bfr(a.z) | (bfr(a.w) << 16);
    o.z = bfr(bb.x) | (bfr(bb.y) << 16);
    o.w = bfr(bb.z) | (bfr(bb.w) << 16);
    *reinterpret_cast<uint4*>(X2 + (size_t)t * 8) = o;

    if (t < 16384) s4[t] = make_float4(0.f, 0.f, 0.f, 0.f);
}

template<int R>
__global__ __launch_bounds__(512)
void caps_route_mfma(const ushort* __restrict__ W3,
                     const ushort* __restrict__ X2,
                     const float* __restrict__ Vacc,
                     float* __restrict__ s)      // [128,32,16] zeroed
{
    __shared__ float pl[2][8][16];   // per-wave softmax partial denoms, dbuf
    __shared__ float tr[8][1024];    // per-wave transpose buffers (32KB)

    const int tid  = threadIdx.x;
    const int lane = tid & 63;
    const int w    = tid >> 6;       // wave 0..7 -> j-tiles w*4..w*4+3
    const int bl   = lane & 15;      // A: k-row ; B: b-col ; C: b-col
    const int kg   = lane >> 4;      // k-slot group (C rows kg*4..kg*4+3)
    const bool lo  = (kg == 0);      // lanes with real K-slots (l = 0..7)
    const int bg   = blockIdx.x >> 7;    // 0..7 batch group
    const int sl   = blockIdx.x & 127;   // i-slice 0..127
    const int i0   = sl * 9;
    const int b0   = bg * 16;

    fab zf;
    #pragma unroll
    for (int q = 0; q < 8; ++q) zf[q] = 0;

    auto loadA = [&](int i, int t) -> fab {
        return lo ? *reinterpret_cast<const fab*>(
                        W3 + (((size_t)i * 32 + w * 4 + t) * 16 + bl) * 8)
                  : zf;
    };
    auto loadB = [&](int i) -> fab {
        return lo ? *reinterpret_cast<const fab*>(
                        X2 + ((size_t)i * 128 + b0 + bl) * 8)
                  : zf;
    };

    // Vacc fragment (i-independent, lane-local), log2 domain
    float Vr[4][4];
    if (R > 0) {
        #pragma unroll
        for (int t = 0; t < 4; ++t)
            #pragma unroll
            for (int r = 0; r < 4; ++r)
                Vr[t][r] = Vacc[((size_t)(b0 + bl) * 32 + w * 4 + t) * 16
                                + kg * 4 + r] * 1.44269504f;
    }

    fcc sacc[4];
    #pragma unroll
    for (int t = 0; t < 4; ++t)
        #pragma unroll
        for (int r = 0; r < 4; ++r) sacc[t][r] = 0.0f;

    auto body = [&](const fab* A, const fab& B, int ii) {
        const fcc cz = {0.0f, 0.0f, 0.0f, 0.0f};
        fcc u[4];
        #pragma unroll
        for (int t = 0; t < 4; ++t)
            u[t] = __builtin_amdgcn_mfma_f32_16x16x32_bf16(A[t], B, cz, 0, 0, 0);

        float cf4[4];
        if (R == 0) {
            #pragma unroll
            for (int t = 0; t < 4; ++t) cf4[t] = 0.03125f;
        } else {
            float e[4];
            float ps = 0.0f;
            #pragma unroll
            for (int t = 0; t < 4; ++t) {
                float p = u[t][0] * Vr[t][0];
                p = fmaf(u[t][1], Vr[t][1], p);
                p = fmaf(u[t][2], Vr[t][2], p);
                p = fmaf(u[t][3], Vr[t][3], p);
                p += __shfl_xor(p, 16);          // combine k-groups
                p += __shfl_xor(p, 32);
                e[t] = exp2f(p);                 // no max-subtract: |p| small
                ps += e[t];
            }
            const int ib = ii & 1;
            if (lane < 16) pl[ib][w][bl] = ps;
            __syncthreads();
            float den = pl[ib][0][bl];
            #pragma unroll
            for (int ww = 1; ww < 8; ++ww) den += pl[ib][ww][bl];
            const float inv = __builtin_amdgcn_rcpf(den);
            #pragma unroll
            for (int t = 0; t < 4; ++t) cf4[t] = e[t] * inv;
        }
        #pragma unroll
        for (int t = 0; t < 4; ++t)
            #pragma unroll
            for (int r = 0; r < 4; ++r)
                sacc[t][r] = fmaf(cf4[t], u[t][r], sacc[t][r]);
    };

    // distance-1 register prefetch; 9 iters = 4x2 + tail
    fab A0[4], A1[4], B0, B1;
    #pragma unroll
    for (int t = 0; t < 4; ++t) A0[t] = loadA(i0, t);
    B0 = loadB(i0);

    for (int g = 0; g < 4; ++g) {
        const int i = 2 * g;
        {
            const int ip = i0 + i + 1;
            #pragma unroll
            for (int t = 0; t < 4; ++t) A1[t] = loadA(ip, t);
            B1 = loadB(ip);
        }
        body(A0, B0, i);
        {
            const int ip = i0 + i + 2;    // g=3 -> i0+8, always valid
            #pragma unroll
            for (int t = 0; t < 4; ++t) A0[t] = loadA(ip, t);
            B0 = loadB(ip);
        }
        body(A1, B1, i + 1);
    }
    body(A0, B0, 8);                      // tail, no prefetch

    // ---- epilogue: per-wave LDS transpose -> 64-contiguous atomics ----
    // sacc[t][r] = s-partial[b0+bl][j=w*4+t][k=kg*4+r]; off = t*16+kg*4+r.
    // DS ops are in-order per wave -> no barrier needed (per-wave region).
    {
        float* ep = &tr[w][0];
        #pragma unroll
        for (int t = 0; t < 4; ++t)
            #pragma unroll
            for (int r = 0; r < 4; ++r) {
                const int off = t * 16 + kg * 4 + r;
                ep[off * 16 + (bl ^ (off & 15))] = sacc[t][r];
            }
        float* sg = s + (size_t)b0 * 512 + w * 64;
        #pragma unroll
        for (int c = 0; c < 16; ++c) {
            const float v = ep[lane * 16 + (c ^ (lane & 15))];
            atomicAdd(&sg[(size_t)c * 512 + lane], v);   // 64 contiguous
        }
    }
}

// ==================== fp32 fallback route (v6 verbatim) ====================
#define WJ        (1152 * 128)
#define I_TILE_F  24
#define NSLICE_F  48

template<int R>
__global__ __launch_bounds__(256)
void caps_route_f32(const float* __restrict__ x,
                    const float* __restrict__ W,
                    const float* __restrict__ Vacc,
                    float* __restrict__ s)
{
    __shared__ float Wt[2][4096];
    __shared__ float xs[8 * 192];

    const int tid  = threadIdx.x;
    const int lane = tid & 63;
    const int wv   = tid >> 6;
    const int j    = lane & 31;
    const int kh   = lane >> 5;
    const int bg   = blockIdx.x / NSLICE_F;
    const int sl   = blockIdx.x % NSLICE_F;
    const int i0   = sl * I_TILE_F;
    const int b0   = bg * 8 + wv * 2;

    const float* wsrc[4];
    #pragma unroll
    for (int t = 0; t < 4; ++t) {
        const int q  = (wv * 4 + t) * 1024 + lane * 16;
        const int rr = q >> 8;
        const int cb = (q & 255) ^ ((rr & 15) << 4);
        const int js = rr & 31;
        const int c  = (rr >> 5) * 64 + (cb >> 2);
        wsrc[t] = W + (size_t)js * WJ + c;
    }

    auto stage = [&](int buf, int i) {
        #pragma unroll
        for (int t = 0; t < 4; ++t)
            __builtin_amdgcn_global_load_lds(
                (const __attribute__((address_space(1))) uint32_t*)
                    (wsrc[t] + (size_t)i * 128),
                (__attribute__((address_space(3))) uint32_t*)
                    &Wt[buf][(wv * 4 + t) * 256], 16, 0, 0);
    };

    stage(0, i0);

    for (int cf = tid; cf < 384; cf += 256) {
        const int bl = cf / 48;
        const int rm = cf - bl * 48;
        float4 v = *reinterpret_cast<const float4*>(
            x + ((size_t)(bg * 8 + bl) * 1152 + i0) * 8 + rm * 4);
        *reinterpret_cast<float4*>(xs + bl * 192 + rm * 4) = v;
    }

    float Vr[2][8];
    if (R > 0) {
        #pragma unroll
        for (int bb = 0; bb < 2; ++bb) {
            const float* vp = Vacc + ((size_t)(b0 + bb) * 32 + j) * 16 + kh * 8;
            const float4 va = *reinterpret_cast<const float4*>(vp);
            const float4 vb = *reinterpret_cast<const float4*>(vp + 4);
            Vr[bb][0] = va.x * 1.44269504f; Vr[bb][1] = va.y * 1.44269504f;
            Vr[bb][2] = va.z * 1.44269504f; Vr[bb][3] = va.w * 1.44269504f;
            Vr[bb][4] = vb.x * 1.44269504f; Vr[bb][5] = vb.y * 1.44269504f;
            Vr[bb][6] = vb.z * 1.44269504f; Vr[bb][7] = vb.w * 1.44269504f;
        }
    }

    float sacc[2][8];
    #pragma unroll
    for (int bb = 0; bb < 2; ++bb)
        #pragma unroll
        for (int kk = 0; kk < 8; ++kk) sacc[bb][kk] = 0.0f;

    __syncthreads();

    const int sw = (j & 15) << 4;

    for (int ii = 0; ii < I_TILE_F; ++ii) {
        const int cur = ii & 1;
        if (ii + 1 < I_TILE_F) stage(cur ^ 1, i0 + ii + 1);

        float4 xa[2], xb[2];
        #pragma unroll
        for (int bb = 0; bb < 2; ++bb) {
            const float* xp = xs + (wv * 2 + bb) * 192 + ii * 8;
            xa[bb] = *reinterpret_cast<const float4*>(xp);
            xb[bb] = *reinterpret_cast<const float4*>(xp + 4);
        }

        const char* lbase = reinterpret_cast<const char*>(&Wt[cur][0]) + lane * 256;

        float u[2][8];
        #pragma unroll
        for (int kk = 0; kk < 8; ++kk) {
            const float4 w0 = *reinterpret_cast<const float4*>(lbase + ((kk * 32) ^ sw));
            const float4 w1 = *reinterpret_cast<const float4*>(lbase + ((kk * 32 + 16) ^ sw));
            #pragma unroll
            for (int bb = 0; bb < 2; ++bb) {
                float acc;
                acc = w0.x * xa[bb].x;
                acc = fmaf(w0.y, xa[bb].y, acc);
                acc = fmaf(w0.z, xa[bb].z, acc);
                acc = fmaf(w0.w, xa[bb].w, acc);
                acc = fmaf(w1.x, xb[bb].x, acc);
                acc = fmaf(w1.y, xb[bb].y, acc);
                acc = fmaf(w1.z, xb[bb].z, acc);
                acc = fmaf(w1.w, xb[bb].w, acc);
                u[bb][kk] = acc;
            }
        }

        if (R == 0) {
            #pragma unroll
            for (int bb = 0; bb < 2; ++bb)
                #pragma unroll
                for (int kk = 0; kk < 8; ++kk)
                    sacc[bb][kk] = fmaf(0.03125f, u[bb][kk], sacc[bb][kk]);
        } else {
            float p0 = u[0][0] * Vr[0][0];
            float p1 = u[1][0] * Vr[1][0];
            #pragma unroll
            for (int kk = 1; kk < 8; ++kk) {
                p0 = fmaf(u[0][kk], Vr[0][kk], p0);
                p1 = fmaf(u[1][kk], Vr[1][kk], p1);
            }
            p0 += __shfl_xor(p0, 32);
            p1 += __shfl_xor(p1, 32);
            const float pq = kh ? p1 : p0;
            const float e  = exp2f(pq);
            float den = e;
            den += __shfl_xor(den, 1);
            den += __shfl_xor(den, 2);
            den += __shfl_xor(den, 4);
            den += __shfl_xor(den, 8);
            den += __shfl_xor(den, 16);
            const float cf_own = e * __builtin_amdgcn_rcpf(den);
            const float cf_oth = __shfl_xor(cf_own, 32);
            const float cf0 = kh ? cf_oth : cf_own;
            const float cf1 = kh ? cf_own : cf_oth;
            #pragma unroll
            for (int kk = 0; kk < 8; ++kk) {
                sacc[0][kk] = fmaf(cf0, u[0][kk], sacc[0][kk]);
                sacc[1][kk] = fmaf(cf1, u[1][kk], sacc[1][kk]);
            }
        }
        __syncthreads();
    }

    {
        float* ep = &Wt[0][0] + wv * 1024;
        #pragma unroll
        for (int bb = 0; bb < 2; ++bb)
            #pragma unroll
            for (int kk = 0; kk < 8; ++kk)
                ep[bb * 512 + j * 16 + ((kh * 8 + kk) ^ ((j >> 1) & 15))] =
                    sacc[bb][kk];

        float* sg = s + (size_t)b0 * 512;
        #pragma unroll
        for (int c = 0; c < 16; ++c) {
            const int m   = c * 64 + lane;
            const int bb2 = m >> 9;
            const int j2  = (m >> 4) & 31;
            const int k2  = m & 15;
            const float v = ep[bb2 * 512 + j2 * 16 + (k2 ^ ((j2 >> 1) & 15))];
            atomicAdd(&sg[m], v);
        }
    }
}

// MODE 0: Vacc = v, zero s;  MODE 1: Vacc += v, zero s;  MODE 2: out = v
template<int MODE>
__global__ __launch_bounds__(256)
void caps_squash(float* __restrict__ s,
                 float* __restrict__ Vacc,
                 float* __restrict__ out)
{
    const int t = blockIdx.x * 256 + threadIdx.x;   // (b,j,k), k fastest
    const float sv = s[t];
    float p = sv * sv;
    p += __shfl_xor(p, 1);
    p += __shfl_xor(p, 2);
    p += __shfl_xor(p, 4);
    p += __shfl_xor(p, 8);
    const float scale = p / ((1.0f + p) * sqrtf(p + 1e-7f));
    const float v = scale * sv;
    if (MODE == 0)      { Vacc[t] = v;  s[t] = 0.0f; }
    else if (MODE == 1) { Vacc[t] += v; s[t] = 0.0f; }
    else                { out[t] = v; }
}

extern "C" void kernel_launch(void* const* d_in, const int* in_sizes, int n_in,
                              void* d_out, int out_size, void* d_ws, size_t ws_size,
                              hipStream_t stream)
{
    const float* x = (const float*)d_in[0];   // [128,1152,8]
    const float* W = (const float*)d_in[1];   // [32,1152,16,8]
    float* out = (float*)d_out;               // [128,32,16]

    const size_t W3B = (size_t)589824 * 16;   // 9,437,184 B
    const size_t X2B = (size_t)147456 * 16;   // 2,359,296 B
    const size_t SB  = (size_t)65536 * sizeof(float);

    if (ws_size >= W3B + X2B + 2 * SB) {
        ushort* W3  = (ushort*)d_ws;
        ushort* X2  = (ushort*)((char*)d_ws + W3B);
        float* Vacc = (float*)((char*)d_ws + W3B + X2B);
        float* sbuf = Vacc + 65536;

        prep_w<<<2304, 256, 0, stream>>>(W, W3);
        prep_x<<<576, 256, 0, stream>>>(x, X2, (float4*)sbuf);

        dim3 grid(1024);   // 8 bgroups x 128 i-slices = 4 WG/CU exact
        dim3 blk(512);
        caps_route_mfma<0><<<grid, blk, 0, stream>>>(W3, X2, Vacc, sbuf);
        caps_squash<0><<<256, 256, 0, stream>>>(sbuf, Vacc, out);
        caps_route_mfma<1><<<grid, blk, 0, stream>>>(W3, X2, Vacc, sbuf);
        caps_squash<1><<<256, 256, 0, stream>>>(sbuf, Vacc, out);
        caps_route_mfma<2><<<grid, blk, 0, stream>>>(W3, X2, Vacc, sbuf);
        caps_squash<2><<<256, 256, 0, stream>>>(sbuf, Vacc, out);
    } else {
        float* Vacc = (float*)d_ws;
        float* sbuf = Vacc + 65536;
        hipMemsetAsync(sbuf, 0, SB, stream);

        dim3 grid(16 * NSLICE_F);  // 768 WGs
        dim3 blk(256);
        caps_route_f32<0><<<grid, blk, 0, stream>>>(x, W, Vacc, sbuf);
        caps_squash<0><<<256, 256, 0, stream>>>(sbuf, Vacc, out);
        caps_route_f32<1><<<grid, blk, 0, stream>>>(x, W, Vacc, sbuf);
        caps_squash<1><<<256, 256, 0, stream>>>(sbuf, Vacc, out);
        caps_route_f32<2><<<grid, blk, 0, stream>>>(x, W, Vacc, sbuf);
        caps_squash<2><<<256, 256, 0, stream>>>(sbuf, Vacc, out);
    }
}

// Round 14
// 143.161 us; speedup vs baseline: 1.0906x; 1.0906x over previous
//
#include <hip/hip_runtime.h>
#include <hip/hip_bf16.h>
#include <stdint.h>

// CapsuleLayer dynamic routing v14 = v12 with privatized s-partials.
// u_hat per i is a GEMM: U^T[(j,k), b] = W_i[(j,k), l] x^T[l, b] via
// mfma_f32_16x16x32_bf16 (M=16 k's of one j, N=16 b, K=32, l=8 real).
// C layout (m89): col=lane&15=b, row=(lane>>4)*4+reg=k.
// v12->v13 A/B showed route time ~ 6us per million epilogue lane-atomics
// (29us@4.2M vs 54us@8.4M): the s-accumulation atomics dominate route.
// v14: each WG stores its disjoint 8192-float partial to a private slab
// s_part[(bg*64+sl)][8192] (plain coalesced stores; the v12 store map is
// exactly flat (b,j,k) within the bg) and squash reduces the 64 slabs.
// No zeroing needed (slabs fully overwritten). Atomic path kept as
// fallback for small ws.

using fab = __attribute__((ext_vector_type(8))) short;   // 8 bf16 = 4 VGPR
using fcc = __attribute__((ext_vector_type(4))) float;   // 4 f32 accum

__device__ __forceinline__ uint32_t bfr(float f) {   // fp32 -> bf16 RTN-even
    uint32_t u = __float_as_uint(f);
    return (u + 0x7fffu + ((u >> 16) & 1u)) >> 16;
}

// W3[((i*32 + j)*16 + k)*8 + l] bf16  (16B per (i,j,k) row)
__global__ __launch_bounds__(256)
void prep_w(const float* __restrict__ W, ushort* __restrict__ W3)
{
    const int t = blockIdx.x * 256 + threadIdx.x;   // (i,j,k), k fastest
    const int k = t & 15, j = (t >> 4) & 31, i = t >> 9;
    const float* src = W + (((size_t)j * 1152 + i) * 16 + k) * 8;
    const float4 a = *reinterpret_cast<const float4*>(src);
    const float4 b = *reinterpret_cast<const float4*>(src + 4);
    uint4 o;
    o.x = bfr(a.x) | (bfr(a.y) << 16);
    o.y = bfr(a.z) | (bfr(a.w) << 16);
    o.z = bfr(b.x) | (bfr(b.y) << 16);
    o.w = bfr(b.z) | (bfr(b.w) << 16);
    *reinterpret_cast<uint4*>(W3 + (size_t)t * 8) = o;
}

// x2T[(i*128 + b)*8 + l] bf16 ; also zeroes sz (256KB, fallback path only)
__global__ __launch_bounds__(256)
void prep_x(const float* __restrict__ x, ushort* __restrict__ X2,
            float4* __restrict__ sz)
{
    const int t = blockIdx.x * 256 + threadIdx.x;   // (i,b), b fastest
    const int b = t & 127, i = t >> 7;
    const float* src = x + ((size_t)b * 1152 + i) * 8;
    const float4 a = *reinterpret_cast<const float4*>(src);
    const float4 bb = *reinterpret_cast<const float4*>(src + 4);
    uint4 o;
    o.x = bfr(a.x) | (bfr(a.y) << 16);
    o.y = bfr(a.z) | (bfr(a.w) << 16);
    o.z = bfr(bb.x) | (bfr(bb.y) << 16);
    o.w = bfr(bb.z) | (bfr(bb.w) << 16);
    *reinterpret_cast<uint4*>(X2 + (size_t)t * 8) = o;

    if (t < 16384) sz[t] = make_float4(0.f, 0.f, 0.f, 0.f);
}

// PRIV=1: store partial slab to s_part[(bg*64+sl)*8192 + ...]
// PRIV=0: atomicAdd into s[b0*512 + ...] (v12 behavior)
template<int R, int PRIV>
__global__ __launch_bounds__(512)
void caps_route_mfma(const ushort* __restrict__ W3,
                     const ushort* __restrict__ X2,
                     const float* __restrict__ Vacc,
                     float* __restrict__ s)
{
    __shared__ float pl[2][8][16];   // per-wave softmax partial denoms, dbuf
    __shared__ float tr[8][1024];    // per-wave transpose buffers (32KB)

    const int tid  = threadIdx.x;
    const int lane = tid & 63;
    const int w    = tid >> 6;       // wave 0..7 -> j-tiles w*4..w*4+3
    const int bl   = lane & 15;      // A: k-row ; B: b-col ; C: b-col
    const int kg   = lane >> 4;      // k-slot group (C rows kg*4..kg*4+3)
    const bool lo  = (kg == 0);      // lanes with real K-slots (l = 0..7)
    const int bg   = blockIdx.x >> 6;    // 0..7 batch group
    const int sl   = blockIdx.x & 63;    // i-slice
    const int i0   = sl * 18;
    const int b0   = bg * 16;

    fab zf;
    #pragma unroll
    for (int q = 0; q < 8; ++q) zf[q] = 0;

    auto loadA = [&](int i, int t) -> fab {
        return lo ? *reinterpret_cast<const fab*>(
                        W3 + (((size_t)i * 32 + w * 4 + t) * 16 + bl) * 8)
                  : zf;
    };
    auto loadB = [&](int i) -> fab {
        return lo ? *reinterpret_cast<const fab*>(
                        X2 + ((size_t)i * 128 + b0 + bl) * 8)
                  : zf;
    };

    // Vacc fragment (i-independent, lane-local), log2 domain
    float Vr[4][4];
    if (R > 0) {
        #pragma unroll
        for (int t = 0; t < 4; ++t)
            #pragma unroll
            for (int r = 0; r < 4; ++r)
                Vr[t][r] = Vacc[((size_t)(b0 + bl) * 32 + w * 4 + t) * 16
                                + kg * 4 + r] * 1.44269504f;
    }

    fcc sacc[4];
    #pragma unroll
    for (int t = 0; t < 4; ++t)
        #pragma unroll
        for (int r = 0; r < 4; ++r) sacc[t][r] = 0.0f;

    auto body = [&](const fab* A, const fab& B, int ii) {
        const fcc cz = {0.0f, 0.0f, 0.0f, 0.0f};
        fcc u[4];
        #pragma unroll
        for (int t = 0; t < 4; ++t)
            u[t] = __builtin_amdgcn_mfma_f32_16x16x32_bf16(A[t], B, cz, 0, 0, 0);

        float cf4[4];
        if (R == 0) {
            #pragma unroll
            for (int t = 0; t < 4; ++t) cf4[t] = 0.03125f;
        } else {
            float e[4];
            float ps = 0.0f;
            #pragma unroll
            for (int t = 0; t < 4; ++t) {
                float p = u[t][0] * Vr[t][0];
                p = fmaf(u[t][1], Vr[t][1], p);
                p = fmaf(u[t][2], Vr[t][2], p);
                p = fmaf(u[t][3], Vr[t][3], p);
                p += __shfl_xor(p, 16);          // combine k-groups
                p += __shfl_xor(p, 32);
                e[t] = exp2f(p);                 // no max-subtract: |p| small
                ps += e[t];
            }
            const int ib = ii & 1;
            if (lane < 16) pl[ib][w][bl] = ps;
            __syncthreads();
            float den = pl[ib][0][bl];
            #pragma unroll
            for (int ww = 1; ww < 8; ++ww) den += pl[ib][ww][bl];
            const float inv = __builtin_amdgcn_rcpf(den);
            #pragma unroll
            for (int t = 0; t < 4; ++t) cf4[t] = e[t] * inv;
        }
        #pragma unroll
        for (int t = 0; t < 4; ++t)
            #pragma unroll
            for (int r = 0; r < 4; ++r)
                sacc[t][r] = fmaf(cf4[t], u[t][r], sacc[t][r]);
    };

    // distance-1 register prefetch, unroll-2 (18 iters, even)
    fab A0[4], A1[4], B0, B1;
    #pragma unroll
    for (int t = 0; t < 4; ++t) A0[t] = loadA(i0, t);
    B0 = loadB(i0);

    for (int ii = 0; ii < 18; ii += 2) {
        {
            const int ip = i0 + ii + 1;
            #pragma unroll
            for (int t = 0; t < 4; ++t) A1[t] = loadA(ip, t);
            B1 = loadB(ip);
        }
        body(A0, B0, ii);
        {
            int ip = i0 + ii + 2;
            if (ip > 1151) ip = 1151;            // clamp (last prefetch unused)
            #pragma unroll
            for (int t = 0; t < 4; ++t) A0[t] = loadA(ip, t);
            B0 = loadB(ip);
        }
        body(A1, B1, ii + 1);
    }

    // ---- epilogue: per-wave LDS transpose -> 64-contiguous writes ----
    // sacc[t][r] = s-partial[b0+bl][j=w*4+t][k=kg*4+r]; off = t*16+kg*4+r.
    // Store map verified: global idx == flat (b,j,k) within the bg slab.
    {
        float* ep = &tr[w][0];
        #pragma unroll
        for (int t = 0; t < 4; ++t)
            #pragma unroll
            for (int r = 0; r < 4; ++r) {
                const int off = t * 16 + kg * 4 + r;
                ep[off * 16 + (bl ^ (off & 15))] = sacc[t][r];
            }
        if (PRIV) {
            float* sg = s + ((size_t)(bg * 64 + sl)) * 8192 + w * 64;
            #pragma unroll
            for (int c = 0; c < 16; ++c) {
                const float v = ep[lane * 16 + (c ^ (lane & 15))];
                sg[(size_t)c * 512 + lane] = v;          // plain store
            }
        } else {
            float* sg = s + (size_t)b0 * 512 + w * 64;
            #pragma unroll
            for (int c = 0; c < 16; ++c) {
                const float v = ep[lane * 16 + (c ^ (lane & 15))];
                atomicAdd(&sg[(size_t)c * 512 + lane], v);
            }
        }
    }
}

// Reduction squash over 64 private slabs per bg.
// MODE 0: Vacc = v;  MODE 1: Vacc += v;  MODE 2: out = v
template<int MODE>
__global__ __launch_bounds__(256)
void caps_squash_red(const float* __restrict__ sp,
                     float* __restrict__ Vacc,
                     float* __restrict__ out)
{
    const int t  = blockIdx.x * 256 + threadIdx.x;  // flat (b,j,k), 65536
    const int bg = t >> 13;                         // b >> 4
    const int m  = t & 8191;                        // (b&15)*512 + j*16 + k
    const float* p = sp + (size_t)(bg * 64) * 8192 + m;
    float sv = 0.0f;
    #pragma unroll
    for (int sl = 0; sl < 64; ++sl) sv += p[(size_t)sl * 8192];

    float pw = sv * sv;
    pw += __shfl_xor(pw, 1);
    pw += __shfl_xor(pw, 2);
    pw += __shfl_xor(pw, 4);
    pw += __shfl_xor(pw, 8);
    const float scale = pw / ((1.0f + pw) * sqrtf(pw + 1e-7f));
    const float v = scale * sv;
    if (MODE == 0)      Vacc[t] = v;
    else if (MODE == 1) Vacc[t] += v;
    else                out[t] = v;
}

// Fallback squash (atomic path): MODE 0/1 also re-zero s
template<int MODE>
__global__ __launch_bounds__(256)
void caps_squash(float* __restrict__ s,
                 float* __restrict__ Vacc,
                 float* __restrict__ out)
{
    const int t = blockIdx.x * 256 + threadIdx.x;   // (b,j,k), k fastest
    const float sv = s[t];
    float p = sv * sv;
    p += __shfl_xor(p, 1);
    p += __shfl_xor(p, 2);
    p += __shfl_xor(p, 4);
    p += __shfl_xor(p, 8);
    const float scale = p / ((1.0f + p) * sqrtf(p + 1e-7f));
    const float v = scale * sv;
    if (MODE == 0)      { Vacc[t] = v;  s[t] = 0.0f; }
    else if (MODE == 1) { Vacc[t] += v; s[t] = 0.0f; }
    else                { out[t] = v; }
}

extern "C" void kernel_launch(void* const* d_in, const int* in_sizes, int n_in,
                              void* d_out, int out_size, void* d_ws, size_t ws_size,
                              hipStream_t stream)
{
    const float* x = (const float*)d_in[0];   // [128,1152,8]
    const float* W = (const float*)d_in[1];   // [32,1152,16,8]
    float* out = (float*)d_out;               // [128,32,16]

    const size_t W3B = (size_t)589824 * 16;   // 9,437,184 B
    const size_t X2B = (size_t)147456 * 16;   // 2,359,296 B
    const size_t SB  = (size_t)65536 * sizeof(float);       // 256 KB
    const size_t SPB = (size_t)512 * 8192 * sizeof(float);  // 16 MB slabs

    ushort* W3  = (ushort*)d_ws;
    ushort* X2  = (ushort*)((char*)d_ws + W3B);
    float* Vacc = (float*)((char*)d_ws + W3B + X2B);

    dim3 blk(512);

    if (ws_size >= W3B + X2B + SB + SPB) {
        float* spart = Vacc + 65536;          // 512 slabs x 8192 f32

        prep_w<<<2304, 256, 0, stream>>>(W, W3);
        prep_x<<<576, 256, 0, stream>>>(x, X2, (float4*)spart);

        dim3 grid(512);    // 8 bgroups x 64 i-slices
        caps_route_mfma<0, 1><<<grid, blk, 0, stream>>>(W3, X2, Vacc, spart);
        caps_squash_red<0><<<256, 256, 0, stream>>>(spart, Vacc, out);
        caps_route_mfma<1, 1><<<grid, blk, 0, stream>>>(W3, X2, Vacc, spart);
        caps_squash_red<1><<<256, 256, 0, stream>>>(spart, Vacc, out);
        caps_route_mfma<2, 1><<<grid, blk, 0, stream>>>(W3, X2, Vacc, spart);
        caps_squash_red<2><<<256, 256, 0, stream>>>(spart, Vacc, out);
    } else {
        // fallback: v12 atomic accumulation (needs zeroed s)
        float* sbuf = Vacc + 65536;

        prep_w<<<2304, 256, 0, stream>>>(W, W3);
        prep_x<<<576, 256, 0, stream>>>(x, X2, (float4*)sbuf);

        dim3 grid(512);
        caps_route_mfma<0, 0><<<grid, blk, 0, stream>>>(W3, X2, Vacc, sbuf);
        caps_squash<0><<<256, 256, 0, stream>>>(sbuf, Vacc, out);
        caps_route_mfma<1, 0><<<grid, blk, 0, stream>>>(W3, X2, Vacc, sbuf);
        caps_squash<1><<<256, 256, 0, stream>>>(sbuf, Vacc, out);
        caps_route_mfma<2, 0><<<grid, blk, 0, stream>>>(W3, X2, Vacc, sbuf);
        caps_squash<2><<<256, 256, 0, stream>>>(sbuf, Vacc, out);
    }
}

// Round 15
// 114.381 us; speedup vs baseline: 1.3650x; 1.2516x over previous
//
#include <hip/hip_runtime.h>
#include <hip/hip_bf16.h>
#include <stdint.h>

// CapsuleLayer dynamic routing v15 = v12 route body, 6 graph nodes (was 8).
// u_hat per i is a GEMM: U^T[(j,k), b] = W_i[(j,k), l] x^T[l, b] via
// mfma_f32_16x16x32_bf16 (M=16 k's of one j, N=16 b, K=32, l=8 real).
// C layout (m89): col=lane&15=b, row=(lane>>4)*4+reg=k.
// Ledger (v10/v12 A/B): kernel time ~73us, inter-node gaps ~40us of 114.
// v15 cuts nodes: (1) ping-pong s0/s1/s2; route<R> recomputes
// Vacc = sum_prior squash_row(s_r) in its prologue (bit-identical formula,
// one float4 + 2 shfl per j-tile) -> both intermediate squash kernels gone;
// (2) prep_w+prep_x merged. v13 (4WG/CU) and v14 (slab reduction) both
// regressed -> reverted; atomic epilogue + 512-WG geometry proven at ~19us.

using fab = __attribute__((ext_vector_type(8))) short;   // 8 bf16 = 4 VGPR
using fcc = __attribute__((ext_vector_type(4))) float;   // 4 f32 accum

__device__ __forceinline__ uint32_t bfr(float f) {   // fp32 -> bf16 RTN-even
    uint32_t u = __float_as_uint(f);
    return (u + 0x7fffu + ((u >> 16) & 1u)) >> 16;
}

// W3[((i*32 + j)*16 + k)*8 + l] bf16 ; blocks < 576 also emit
// X2[(i*128 + b)*8 + l] bf16.
__global__ __launch_bounds__(256)
void prep(const float* __restrict__ W, const float* __restrict__ x,
          ushort* __restrict__ W3, ushort* __restrict__ X2)
{
    const int t = blockIdx.x * 256 + threadIdx.x;
    {
        const int k = t & 15, j = (t >> 4) & 31, i = t >> 9;
        const float* src = W + (((size_t)j * 1152 + i) * 16 + k) * 8;
        const float4 a = *reinterpret_cast<const float4*>(src);
        const float4 b = *reinterpret_cast<const float4*>(src + 4);
        uint4 o;
        o.x = bfr(a.x) | (bfr(a.y) << 16);
        o.y = bfr(a.z) | (bfr(a.w) << 16);
        o.z = bfr(b.x) | (bfr(b.y) << 16);
        o.w = bfr(b.z) | (bfr(b.w) << 16);
        *reinterpret_cast<uint4*>(W3 + (size_t)t * 8) = o;
    }
    if (t < 147456) {
        const int b = t & 127, i = t >> 7;
        const float* src = x + ((size_t)b * 1152 + i) * 8;
        const float4 a = *reinterpret_cast<const float4*>(src);
        const float4 bb = *reinterpret_cast<const float4*>(src + 4);
        uint4 o;
        o.x = bfr(a.x) | (bfr(a.y) << 16);
        o.y = bfr(a.z) | (bfr(a.w) << 16);
        o.z = bfr(bb.x) | (bfr(bb.y) << 16);
        o.w = bfr(bb.z) | (bfr(bb.w) << 16);
        *reinterpret_cast<uint4*>(X2 + (size_t)t * 8) = o;
    }
}

// R=0: uniform c, atomics -> sout(=s0).
// R=1: Vr = squash_row(s0), atomics -> sout(=s1).
// R=2: Vr = squash_row(s0)+squash_row(s1), atomics -> sout(=s2).
template<int R>
__global__ __launch_bounds__(512)
void caps_route_mfma(const ushort* __restrict__ W3,
                     const ushort* __restrict__ X2,
                     const float* __restrict__ s0,
                     const float* __restrict__ s1,
                     float* __restrict__ sout)
{
    __shared__ float pl[2][8][16];   // per-wave softmax partial denoms, dbuf
    __shared__ float tr[8][1024];    // per-wave transpose buffers (32KB)

    const int tid  = threadIdx.x;
    const int lane = tid & 63;
    const int w    = tid >> 6;       // wave 0..7 -> j-tiles w*4..w*4+3
    const int bl   = lane & 15;      // A: k-row ; B: b-col ; C: b-col
    const int kg   = lane >> 4;      // k-slot group (C rows kg*4..kg*4+3)
    const bool lo  = (kg == 0);      // lanes with real K-slots (l = 0..7)
    const int bg   = blockIdx.x >> 6;    // 0..7 batch group
    const int sl   = blockIdx.x & 63;    // i-slice
    const int i0   = sl * 18;
    const int b0   = bg * 16;

    fab zf;
    #pragma unroll
    for (int q = 0; q < 8; ++q) zf[q] = 0;

    auto loadA = [&](int i, int t) -> fab {
        return lo ? *reinterpret_cast<const fab*>(
                        W3 + (((size_t)i * 32 + w * 4 + t) * 16 + bl) * 8)
                  : zf;
    };
    auto loadB = [&](int i) -> fab {
        return lo ? *reinterpret_cast<const fab*>(
                        X2 + ((size_t)i * 128 + b0 + bl) * 8)
                  : zf;
    };

    // Vr = accumulated squash of prior rounds, recomputed from raw s
    // (4 kg-lanes share row (b0+bl, j); xor16+xor32 completes the norm).
    float Vr[4][4];
    if (R > 0) {
        #pragma unroll
        for (int t = 0; t < 4; ++t) {
            const size_t ro = ((size_t)(b0 + bl) * 32 + w * 4 + t) * 16 + kg * 4;
            const float4 a = *reinterpret_cast<const float4*>(s0 + ro);
            float q = a.x * a.x + a.y * a.y + a.z * a.z + a.w * a.w;
            q += __shfl_xor(q, 16);
            q += __shfl_xor(q, 32);
            const float sc = q / ((1.0f + q) * sqrtf(q + 1e-7f)) * 1.44269504f;
            Vr[t][0] = a.x * sc; Vr[t][1] = a.y * sc;
            Vr[t][2] = a.z * sc; Vr[t][3] = a.w * sc;
            if (R == 2) {
                const float4 b = *reinterpret_cast<const float4*>(s1 + ro);
                float q1 = b.x * b.x + b.y * b.y + b.z * b.z + b.w * b.w;
                q1 += __shfl_xor(q1, 16);
                q1 += __shfl_xor(q1, 32);
                const float sc1 =
                    q1 / ((1.0f + q1) * sqrtf(q1 + 1e-7f)) * 1.44269504f;
                Vr[t][0] += b.x * sc1; Vr[t][1] += b.y * sc1;
                Vr[t][2] += b.z * sc1; Vr[t][3] += b.w * sc1;
            }
        }
    }

    fcc sacc[4];
    #pragma unroll
    for (int t = 0; t < 4; ++t)
        #pragma unroll
        for (int r = 0; r < 4; ++r) sacc[t][r] = 0.0f;

    auto body = [&](const fab* A, const fab& B, int ii) {
        const fcc cz = {0.0f, 0.0f, 0.0f, 0.0f};
        fcc u[4];
        #pragma unroll
        for (int t = 0; t < 4; ++t)
            u[t] = __builtin_amdgcn_mfma_f32_16x16x32_bf16(A[t], B, cz, 0, 0, 0);

        float cf4[4];
        if (R == 0) {
            #pragma unroll
            for (int t = 0; t < 4; ++t) cf4[t] = 0.03125f;
        } else {
            float e[4];
            float ps = 0.0f;
            #pragma unroll
            for (int t = 0; t < 4; ++t) {
                float p = u[t][0] * Vr[t][0];
                p = fmaf(u[t][1], Vr[t][1], p);
                p = fmaf(u[t][2], Vr[t][2], p);
                p = fmaf(u[t][3], Vr[t][3], p);
                p += __shfl_xor(p, 16);          // combine k-groups
                p += __shfl_xor(p, 32);
                e[t] = exp2f(p);                 // no max-subtract: |p| small
                ps += e[t];
            }
            const int ib = ii & 1;
            if (lane < 16) pl[ib][w][bl] = ps;
            __syncthreads();
            float den = pl[ib][0][bl];
            #pragma unroll
            for (int ww = 1; ww < 8; ++ww) den += pl[ib][ww][bl];
            const float inv = __builtin_amdgcn_rcpf(den);
            #pragma unroll
            for (int t = 0; t < 4; ++t) cf4[t] = e[t] * inv;
        }
        #pragma unroll
        for (int t = 0; t < 4; ++t)
            #pragma unroll
            for (int r = 0; r < 4; ++r)
                sacc[t][r] = fmaf(cf4[t], u[t][r], sacc[t][r]);
    };

    // distance-1 register prefetch, unroll-2 (18 iters, even)
    fab A0[4], A1[4], B0, B1;
    #pragma unroll
    for (int t = 0; t < 4; ++t) A0[t] = loadA(i0, t);
    B0 = loadB(i0);

    for (int ii = 0; ii < 18; ii += 2) {
        {
            const int ip = i0 + ii + 1;
            #pragma unroll
            for (int t = 0; t < 4; ++t) A1[t] = loadA(ip, t);
            B1 = loadB(ip);
        }
        body(A0, B0, ii);
        {
            int ip = i0 + ii + 2;
            if (ip > 1151) ip = 1151;            // clamp (last prefetch unused)
            #pragma unroll
            for (int t = 0; t < 4; ++t) A0[t] = loadA(ip, t);
            B0 = loadB(ip);
        }
        body(A1, B1, ii + 1);
    }

    // ---- epilogue: per-wave LDS transpose -> 64-contiguous atomics ----
    // sacc[t][r] = s-partial[b0+bl][j=w*4+t][k=kg*4+r]; off = t*16+kg*4+r.
    {
        float* ep = &tr[w][0];
        #pragma unroll
        for (int t = 0; t < 4; ++t)
            #pragma unroll
            for (int r = 0; r < 4; ++r) {
                const int off = t * 16 + kg * 4 + r;
                ep[off * 16 + (bl ^ (off & 15))] = sacc[t][r];
            }
        float* sg = sout + (size_t)b0 * 512 + w * 64;
        #pragma unroll
        for (int c = 0; c < 16; ++c) {
            const float v = ep[lane * 16 + (c ^ (lane & 15))];
            atomicAdd(&sg[(size_t)c * 512 + lane], v);   // 64 contiguous
        }
    }
}

// out = squash(s2)
__global__ __launch_bounds__(256)
void caps_squash_out(const float* __restrict__ s2, float* __restrict__ out)
{
    const int t = blockIdx.x * 256 + threadIdx.x;   // (b,j,k), k fastest
    const float sv = s2[t];
    float p = sv * sv;
    p += __shfl_xor(p, 1);
    p += __shfl_xor(p, 2);
    p += __shfl_xor(p, 4);
    p += __shfl_xor(p, 8);
    const float scale = p / ((1.0f + p) * sqrtf(p + 1e-7f));
    out[t] = scale * sv;
}

// ==================== fp32 fallback route (v6 verbatim) ====================
#define WJ        (1152 * 128)
#define I_TILE_F  24
#define NSLICE_F  48

template<int R>
__global__ __launch_bounds__(256)
void caps_route_f32(const float* __restrict__ x,
                    const float* __restrict__ W,
                    const float* __restrict__ Vacc,
                    float* __restrict__ s)
{
    __shared__ float Wt[2][4096];
    __shared__ float xs[8 * 192];

    const int tid  = threadIdx.x;
    const int lane = tid & 63;
    const int wv   = tid >> 6;
    const int j    = lane & 31;
    const int kh   = lane >> 5;
    const int bg   = blockIdx.x / NSLICE_F;
    const int sl   = blockIdx.x % NSLICE_F;
    const int i0   = sl * I_TILE_F;
    const int b0   = bg * 8 + wv * 2;

    const float* wsrc[4];
    #pragma unroll
    for (int t = 0; t < 4; ++t) {
        const int q  = (wv * 4 + t) * 1024 + lane * 16;
        const int rr = q >> 8;
        const int cb = (q & 255) ^ ((rr & 15) << 4);
        const int js = rr & 31;
        const int c  = (rr >> 5) * 64 + (cb >> 2);
        wsrc[t] = W + (size_t)js * WJ + c;
    }

    auto stage = [&](int buf, int i) {
        #pragma unroll
        for (int t = 0; t < 4; ++t)
            __builtin_amdgcn_global_load_lds(
                (const __attribute__((address_space(1))) uint32_t*)
                    (wsrc[t] + (size_t)i * 128),
                (__attribute__((address_space(3))) uint32_t*)
                    &Wt[buf][(wv * 4 + t) * 256], 16, 0, 0);
    };

    stage(0, i0);

    for (int cf = tid; cf < 384; cf += 256) {
        const int bl = cf / 48;
        const int rm = cf - bl * 48;
        float4 v = *reinterpret_cast<const float4*>(
            x + ((size_t)(bg * 8 + bl) * 1152 + i0) * 8 + rm * 4);
        *reinterpret_cast<float4*>(xs + bl * 192 + rm * 4) = v;
    }

    float Vr[2][8];
    if (R > 0) {
        #pragma unroll
        for (int bb = 0; bb < 2; ++bb) {
            const float* vp = Vacc + ((size_t)(b0 + bb) * 32 + j) * 16 + kh * 8;
            const float4 va = *reinterpret_cast<const float4*>(vp);
            const float4 vb = *reinterpret_cast<const float4*>(vp + 4);
            Vr[bb][0] = va.x * 1.44269504f; Vr[bb][1] = va.y * 1.44269504f;
            Vr[bb][2] = va.z * 1.44269504f; Vr[bb][3] = va.w * 1.44269504f;
            Vr[bb][4] = vb.x * 1.44269504f; Vr[bb][5] = vb.y * 1.44269504f;
            Vr[bb][6] = vb.z * 1.44269504f; Vr[bb][7] = vb.w * 1.44269504f;
        }
    }

    float sacc[2][8];
    #pragma unroll
    for (int bb = 0; bb < 2; ++bb)
        #pragma unroll
        for (int kk = 0; kk < 8; ++kk) sacc[bb][kk] = 0.0f;

    __syncthreads();

    const int sw = (j & 15) << 4;

    for (int ii = 0; ii < I_TILE_F; ++ii) {
        const int cur = ii & 1;
        if (ii + 1 < I_TILE_F) stage(cur ^ 1, i0 + ii + 1);

        float4 xa[2], xb[2];
        #pragma unroll
        for (int bb = 0; bb < 2; ++bb) {
            const float* xp = xs + (wv * 2 + bb) * 192 + ii * 8;
            xa[bb] = *reinterpret_cast<const float4*>(xp);
            xb[bb] = *reinterpret_cast<const float4*>(xp + 4);
        }

        const char* lbase = reinterpret_cast<const char*>(&Wt[cur][0]) + lane * 256;

        float u[2][8];
        #pragma unroll
        for (int kk = 0; kk < 8; ++kk) {
            const float4 w0 = *reinterpret_cast<const float4*>(lbase + ((kk * 32) ^ sw));
            const float4 w1 = *reinterpret_cast<const float4*>(lbase + ((kk * 32 + 16) ^ sw));
            #pragma unroll
            for (int bb = 0; bb < 2; ++bb) {
                float acc;
                acc = w0.x * xa[bb].x;
                acc = fmaf(w0.y, xa[bb].y, acc);
                acc = fmaf(w0.z, xa[bb].z, acc);
                acc = fmaf(w0.w, xa[bb].w, acc);
                acc = fmaf(w1.x, xb[bb].x, acc);
                acc = fmaf(w1.y, xb[bb].y, acc);
                acc = fmaf(w1.z, xb[bb].z, acc);
                acc = fmaf(w1.w, xb[bb].w, acc);
                u[bb][kk] = acc;
            }
        }

        if (R == 0) {
            #pragma unroll
            for (int bb = 0; bb < 2; ++bb)
                #pragma unroll
                for (int kk = 0; kk < 8; ++kk)
                    sacc[bb][kk] = fmaf(0.03125f, u[bb][kk], sacc[bb][kk]);
        } else {
            float p0 = u[0][0] * Vr[0][0];
            float p1 = u[1][0] * Vr[1][0];
            #pragma unroll
            for (int kk = 1; kk < 8; ++kk) {
                p0 = fmaf(u[0][kk], Vr[0][kk], p0);
                p1 = fmaf(u[1][kk], Vr[1][kk], p1);
            }
            p0 += __shfl_xor(p0, 32);
            p1 += __shfl_xor(p1, 32);
            const float pq = kh ? p1 : p0;
            const float e  = exp2f(pq);
            float den = e;
            den += __shfl_xor(den, 1);
            den += __shfl_xor(den, 2);
            den += __shfl_xor(den, 4);
            den += __shfl_xor(den, 8);
            den += __shfl_xor(den, 16);
            const float cf_own = e * __builtin_amdgcn_rcpf(den);
            const float cf_oth = __shfl_xor(cf_own, 32);
            const float cf0 = kh ? cf_oth : cf_own;
            const float cf1 = kh ? cf_own : cf_oth;
            #pragma unroll
            for (int kk = 0; kk < 8; ++kk) {
                sacc[0][kk] = fmaf(cf0, u[0][kk], sacc[0][kk]);
                sacc[1][kk] = fmaf(cf1, u[1][kk], sacc[1][kk]);
            }
        }
        __syncthreads();
    }

    {
        float* ep = &Wt[0][0] + wv * 1024;
        #pragma unroll
        for (int bb = 0; bb < 2; ++bb)
            #pragma unroll
            for (int kk = 0; kk < 8; ++kk)
                ep[bb * 512 + j * 16 + ((kh * 8 + kk) ^ ((j >> 1) & 15))] =
                    sacc[bb][kk];

        float* sg = s + (size_t)b0 * 512;
        #pragma unroll
        for (int c = 0; c < 16; ++c) {
            const int m   = c * 64 + lane;
            const int bb2 = m >> 9;
            const int j2  = (m >> 4) & 31;
            const int k2  = m & 15;
            const float v = ep[bb2 * 512 + j2 * 16 + (k2 ^ ((j2 >> 1) & 15))];
            atomicAdd(&sg[m], v);
        }
    }
}

// Fallback squash. MODE 0: Vacc = v, zero s; 1: Vacc += v, zero s; 2: out = v
template<int MODE>
__global__ __launch_bounds__(256)
void caps_squash(float* __restrict__ s,
                 float* __restrict__ Vacc,
                 float* __restrict__ out)
{
    const int t = blockIdx.x * 256 + threadIdx.x;
    const float sv = s[t];
    float p = sv * sv;
    p += __shfl_xor(p, 1);
    p += __shfl_xor(p, 2);
    p += __shfl_xor(p, 4);
    p += __shfl_xor(p, 8);
    const float scale = p / ((1.0f + p) * sqrtf(p + 1e-7f));
    const float v = scale * sv;
    if (MODE == 0)      { Vacc[t] = v;  s[t] = 0.0f; }
    else if (MODE == 1) { Vacc[t] += v; s[t] = 0.0f; }
    else                { out[t] = v; }
}

extern "C" void kernel_launch(void* const* d_in, const int* in_sizes, int n_in,
                              void* d_out, int out_size, void* d_ws, size_t ws_size,
                              hipStream_t stream)
{
    const float* x = (const float*)d_in[0];   // [128,1152,8]
    const float* W = (const float*)d_in[1];   // [32,1152,16,8]
    float* out = (float*)d_out;               // [128,32,16]

    const size_t W3B = (size_t)589824 * 16;   // 9,437,184 B
    const size_t X2B = (size_t)147456 * 16;   // 2,359,296 B
    const size_t SB  = (size_t)65536 * sizeof(float);   // 256 KB

    if (ws_size >= W3B + X2B + 3 * SB) {
        ushort* W3 = (ushort*)d_ws;
        ushort* X2 = (ushort*)((char*)d_ws + W3B);
        float* s0  = (float*)((char*)d_ws + W3B + X2B);
        float* s1  = s0 + 65536;
        float* s2  = s1 + 65536;

        hipMemsetAsync(s0, 0, 3 * SB, stream);
        prep<<<2304, 256, 0, stream>>>(W, x, W3, X2);

        dim3 grid(512);    // 8 bgroups x 64 i-slices
        dim3 blk(512);
        caps_route_mfma<0><<<grid, blk, 0, stream>>>(W3, X2, s0, s0, s0);
        caps_route_mfma<1><<<grid, blk, 0, stream>>>(W3, X2, s0, s0, s1);
        caps_route_mfma<2><<<grid, blk, 0, stream>>>(W3, X2, s0, s1, s2);
        caps_squash_out<<<256, 256, 0, stream>>>(s2, out);
    } else {
        float* Vacc = (float*)d_ws;
        float* sbuf = Vacc + 65536;
        hipMemsetAsync(sbuf, 0, SB, stream);

        dim3 grid(16 * NSLICE_F);  // 768 WGs
        dim3 blk(256);
        caps_route_f32<0><<<grid, blk, 0, stream>>>(x, W, Vacc, sbuf);
        caps_squash<0><<<256, 256, 0, stream>>>(sbuf, Vacc, out);
        caps_route_f32<1><<<grid, blk, 0, stream>>>(x, W, Vacc, sbuf);
        caps_squash<1><<<256, 256, 0, stream>>>(sbuf, Vacc, out);
        caps_route_f32<2><<<grid, blk, 0, stream>>>(x, W, Vacc, sbuf);
        caps_squash<2><<<256, 256, 0, stream>>>(sbuf, Vacc, out);
    }
}

// Round 16
// 105.684 us; speedup vs baseline: 1.4774x; 1.0823x over previous
//
#include <hip/hip_runtime.h>
#include <hip/hip_bf16.h>
#include <stdint.h>

// CapsuleLayer dynamic routing v16.
// R0 repacked as dense GEMM: s0 = (1/32) sum_{i,l} W*x -> (i,l) packed into
// full K=32 (kg lane-group = which i of a quad; no zero padding, no softmax,
// no barriers, 5 MFMA-steps/wave instead of 18).
// R1/R2: pair-softmax — even-i u/e buffered in regs, one barrier per PAIR
// (9 instead of 18), pl[...][bl][2] even/odd slots, float2 den reads.
// Epilogue / prep / ping-pong s0,s1,s2 + Vr-recompute prologue: v12/v15
// proven parts, unchanged.

using fab = __attribute__((ext_vector_type(8))) short;   // 8 bf16 = 4 VGPR
using fcc = __attribute__((ext_vector_type(4))) float;   // 4 f32 accum

__device__ __forceinline__ uint32_t bfr(float f) {   // fp32 -> bf16 RTN-even
    uint32_t u = __float_as_uint(f);
    return (u + 0x7fffu + ((u >> 16) & 1u)) >> 16;
}

// W3[((i*32 + j)*16 + k)*8 + l] bf16 ; blocks < 576 also emit
// X2[(i*128 + b)*8 + l] bf16.
__global__ __launch_bounds__(256)
void prep(const float* __restrict__ W, const float* __restrict__ x,
          ushort* __restrict__ W3, ushort* __restrict__ X2)
{
    const int t = blockIdx.x * 256 + threadIdx.x;
    {
        const int k = t & 15, j = (t >> 4) & 31, i = t >> 9;
        const float* src = W + (((size_t)j * 1152 + i) * 16 + k) * 8;
        const float4 a = *reinterpret_cast<const float4*>(src);
        const float4 b = *reinterpret_cast<const float4*>(src + 4);
        uint4 o;
        o.x = bfr(a.x) | (bfr(a.y) << 16);
        o.y = bfr(a.z) | (bfr(a.w) << 16);
        o.z = bfr(b.x) | (bfr(b.y) << 16);
        o.w = bfr(b.z) | (bfr(b.w) << 16);
        *reinterpret_cast<uint4*>(W3 + (size_t)t * 8) = o;
    }
    if (t < 147456) {
        const int b = t & 127, i = t >> 7;
        const float* src = x + ((size_t)b * 1152 + i) * 8;
        const float4 a = *reinterpret_cast<const float4*>(src);
        const float4 bb = *reinterpret_cast<const float4*>(src + 4);
        uint4 o;
        o.x = bfr(a.x) | (bfr(a.y) << 16);
        o.y = bfr(a.z) | (bfr(a.w) << 16);
        o.z = bfr(bb.x) | (bfr(bb.y) << 16);
        o.w = bfr(bb.z) | (bfr(bb.w) << 16);
        *reinterpret_cast<uint4*>(X2 + (size_t)t * 8) = o;
    }
}

// ============ R0: packed (i,l) K=32 GEMM, no softmax, no barriers ==========
__global__ __launch_bounds__(512)
void caps_route0(const ushort* __restrict__ W3,
                 const ushort* __restrict__ X2,
                 float* __restrict__ sout)
{
    __shared__ float tr[8][1024];

    const int tid  = threadIdx.x;
    const int lane = tid & 63;
    const int w    = tid >> 6;
    const int bl   = lane & 15;
    const int kg   = lane >> 4;          // 0..3: which i of the quad / k-row grp
    const int bg   = blockIdx.x >> 6;
    const int sl   = blockIdx.x & 63;
    const int i0   = sl * 18;
    const int b0   = bg * 16;

    fab zf;
    #pragma unroll
    for (int q = 0; q < 8; ++q) zf[q] = 0;

    // quad step g: K-slot group kg holds (i = i0+4g+kg, l=0..7). All lanes real.
    auto loadAq = [&](int g, int t, bool ok) -> fab {
        return ok ? *reinterpret_cast<const fab*>(
                       W3 + (((size_t)(i0 + 4 * g + kg) * 32 + w * 4 + t) * 16 + bl) * 8)
                  : zf;
    };
    auto loadBq = [&](int g, bool ok) -> fab {
        return ok ? *reinterpret_cast<const fab*>(
                       X2 + ((size_t)(i0 + 4 * g + kg) * 128 + b0 + bl) * 8)
                  : zf;
    };

    fcc sacc[4];
    #pragma unroll
    for (int t = 0; t < 4; ++t)
        #pragma unroll
        for (int r = 0; r < 4; ++r) sacc[t][r] = 0.0f;

    // 5 steps (g=0..3 full quads; g=4 covers i0+16,i0+17 via kg<2), dist-1 pf
    fab Ac[4], An[4], Bc, Bn;
    #pragma unroll
    for (int t = 0; t < 4; ++t) Ac[t] = loadAq(0, t, true);
    Bc = loadBq(0, true);

    #pragma unroll
    for (int g = 0; g < 5; ++g) {
        if (g < 4) {
            const bool ok = (g + 1 < 4) | (kg < 2);
            #pragma unroll
            for (int t = 0; t < 4; ++t) An[t] = loadAq(g + 1, t, ok);
            Bn = loadBq(g + 1, ok);
        }
        #pragma unroll
        for (int t = 0; t < 4; ++t)
            sacc[t] = __builtin_amdgcn_mfma_f32_16x16x32_bf16(Ac[t], Bc, sacc[t], 0, 0, 0);
        if (g < 4) {
            #pragma unroll
            for (int t = 0; t < 4; ++t) Ac[t] = An[t];
            Bc = Bn;
        }
    }

    // epilogue: scale 1/32, per-wave LDS transpose -> 64-contiguous atomics
    {
        float* ep = &tr[w][0];
        #pragma unroll
        for (int t = 0; t < 4; ++t)
            #pragma unroll
            for (int r = 0; r < 4; ++r) {
                const int off = t * 16 + kg * 4 + r;
                ep[off * 16 + (bl ^ (off & 15))] = sacc[t][r] * 0.03125f;
            }
        float* sg = sout + (size_t)b0 * 512 + w * 64;
        #pragma unroll
        for (int c = 0; c < 16; ++c) {
            const float v = ep[lane * 16 + (c ^ (lane & 15))];
            atomicAdd(&sg[(size_t)c * 512 + lane], v);
        }
    }
}

// ============ R1/R2: per-i MFMA + pair-softmax (1 barrier / 2 i) ===========
template<int R>
__global__ __launch_bounds__(512, 4)
void caps_route_sm(const ushort* __restrict__ W3,
                   const ushort* __restrict__ X2,
                   const float* __restrict__ s0,
                   const float* __restrict__ s1,
                   float* __restrict__ sout)
{
    __shared__ float pl[2][8][16][2];    // [pairbuf][w][b][even/odd]
    __shared__ float tr[8][1024];

    const int tid  = threadIdx.x;
    const int lane = tid & 63;
    const int w    = tid >> 6;
    const int bl   = lane & 15;
    const int kg   = lane >> 4;          // 0..3
    const bool lo  = (kg == 0);          // K-slots 0..7 real (l = 0..7)
    const int bg   = blockIdx.x >> 6;
    const int sl   = blockIdx.x & 63;
    const int i0   = sl * 18;
    const int b0   = bg * 16;

    fab zf;
    #pragma unroll
    for (int q = 0; q < 8; ++q) zf[q] = 0;

    auto loadA = [&](int i, int t) -> fab {
        return lo ? *reinterpret_cast<const fab*>(
                        W3 + (((size_t)i * 32 + w * 4 + t) * 16 + bl) * 8)
                  : zf;
    };
    auto loadB = [&](int i) -> fab {
        return lo ? *reinterpret_cast<const fab*>(
                        X2 + ((size_t)i * 128 + b0 + bl) * 8)
                  : zf;
    };

    // Vr = accumulated squash of prior rounds, recomputed from raw s
    float Vr[4][4];
    #pragma unroll
    for (int t = 0; t < 4; ++t) {
        const size_t ro = ((size_t)(b0 + bl) * 32 + w * 4 + t) * 16 + kg * 4;
        const float4 a = *reinterpret_cast<const float4*>(s0 + ro);
        float q = a.x * a.x + a.y * a.y + a.z * a.z + a.w * a.w;
        q += __shfl_xor(q, 16);
        q += __shfl_xor(q, 32);
        const float sc = q / ((1.0f + q) * sqrtf(q + 1e-7f)) * 1.44269504f;
        Vr[t][0] = a.x * sc; Vr[t][1] = a.y * sc;
        Vr[t][2] = a.z * sc; Vr[t][3] = a.w * sc;
        if (R == 2) {
            const float4 b = *reinterpret_cast<const float4*>(s1 + ro);
            float q1 = b.x * b.x + b.y * b.y + b.z * b.z + b.w * b.w;
            q1 += __shfl_xor(q1, 16);
            q1 += __shfl_xor(q1, 32);
            const float sc1 = q1 / ((1.0f + q1) * sqrtf(q1 + 1e-7f)) * 1.44269504f;
            Vr[t][0] += b.x * sc1; Vr[t][1] += b.y * sc1;
            Vr[t][2] += b.z * sc1; Vr[t][3] += b.w * sc1;
        }
    }

    fcc sacc[4];
    #pragma unroll
    for (int t = 0; t < 4; ++t)
        #pragma unroll
        for (int r = 0; r < 4; ++r) sacc[t][r] = 0.0f;

    const fcc cz = {0.0f, 0.0f, 0.0f, 0.0f};

    fab A0[4], A1[4], B0, B1;
    #pragma unroll
    for (int t = 0; t < 4; ++t) A0[t] = loadA(i0, t);
    B0 = loadB(i0);

    for (int pp = 0; pp < 9; ++pp) {
        const int ie = i0 + 2 * pp;
        // prefetch odd i
        #pragma unroll
        for (int t = 0; t < 4; ++t) A1[t] = loadA(ie + 1, t);
        B1 = loadB(ie + 1);

        // even i: MFMA + logits + exp (hold ue/ee across barrier)
        fcc ue[4];
        #pragma unroll
        for (int t = 0; t < 4; ++t)
            ue[t] = __builtin_amdgcn_mfma_f32_16x16x32_bf16(A0[t], B0, cz, 0, 0, 0);
        float ee[4], pse = 0.0f;
        #pragma unroll
        for (int t = 0; t < 4; ++t) {
            float p = ue[t][0] * Vr[t][0];
            p = fmaf(ue[t][1], Vr[t][1], p);
            p = fmaf(ue[t][2], Vr[t][2], p);
            p = fmaf(ue[t][3], Vr[t][3], p);
            p += __shfl_xor(p, 16);
            p += __shfl_xor(p, 32);
            ee[t] = exp2f(p);
            pse += ee[t];
        }
        if (lane < 16) pl[pp & 1][w][bl][0] = pse;

        // prefetch next even i
        if (pp < 8) {
            #pragma unroll
            for (int t = 0; t < 4; ++t) A0[t] = loadA(ie + 2, t);
            B0 = loadB(ie + 2);
        }

        // odd i: MFMA + logits + exp
        fcc uo[4];
        #pragma unroll
        for (int t = 0; t < 4; ++t)
            uo[t] = __builtin_amdgcn_mfma_f32_16x16x32_bf16(A1[t], B1, cz, 0, 0, 0);
        float eo[4], pso = 0.0f;
        #pragma unroll
        for (int t = 0; t < 4; ++t) {
            float p = uo[t][0] * Vr[t][0];
            p = fmaf(uo[t][1], Vr[t][1], p);
            p = fmaf(uo[t][2], Vr[t][2], p);
            p = fmaf(uo[t][3], Vr[t][3], p);
            p += __shfl_xor(p, 16);
            p += __shfl_xor(p, 32);
            eo[t] = exp2f(p);
            pso += eo[t];
        }
        if (lane >= 16 && lane < 32) pl[pp & 1][w][bl][1] = pso;

        __syncthreads();   // one barrier per PAIR

        float dene = 0.0f, deno = 0.0f;
        #pragma unroll
        for (int ww = 0; ww < 8; ++ww) {
            const float2 d = *reinterpret_cast<const float2*>(&pl[pp & 1][ww][bl][0]);
            dene += d.x;
            deno += d.y;
        }
        const float inve = __builtin_amdgcn_rcpf(dene);
        const float invo = __builtin_amdgcn_rcpf(deno);
        #pragma unroll
        for (int t = 0; t < 4; ++t) {
            const float cfe = ee[t] * inve;
            const float cfo = eo[t] * invo;
            #pragma unroll
            for (int r = 0; r < 4; ++r) {
                sacc[t][r] = fmaf(cfe, ue[t][r], sacc[t][r]);
                sacc[t][r] = fmaf(cfo, uo[t][r], sacc[t][r]);
            }
        }
    }

    // epilogue: per-wave LDS transpose -> 64-contiguous atomics
    {
        float* ep = &tr[w][0];
        #pragma unroll
        for (int t = 0; t < 4; ++t)
            #pragma unroll
            for (int r = 0; r < 4; ++r) {
                const int off = t * 16 + kg * 4 + r;
                ep[off * 16 + (bl ^ (off & 15))] = sacc[t][r];
            }
        float* sg = sout + (size_t)b0 * 512 + w * 64;
        #pragma unroll
        for (int c = 0; c < 16; ++c) {
            const float v = ep[lane * 16 + (c ^ (lane & 15))];
            atomicAdd(&sg[(size_t)c * 512 + lane], v);
        }
    }
}

// out = squash(s2)
__global__ __launch_bounds__(256)
void caps_squash_out(const float* __restrict__ s2, float* __restrict__ out)
{
    const int t = blockIdx.x * 256 + threadIdx.x;
    const float sv = s2[t];
    float p = sv * sv;
    p += __shfl_xor(p, 1);
    p += __shfl_xor(p, 2);
    p += __shfl_xor(p, 4);
    p += __shfl_xor(p, 8);
    const float scale = p / ((1.0f + p) * sqrtf(p + 1e-7f));
    out[t] = scale * sv;
}

// ==================== fp32 fallback route (v6 verbatim) ====================
#define WJ        (1152 * 128)
#define I_TILE_F  24
#define NSLICE_F  48

template<int R>
__global__ __launch_bounds__(256)
void caps_route_f32(const float* __restrict__ x,
                    const float* __restrict__ W,
                    const float* __restrict__ Vacc,
                    float* __restrict__ s)
{
    __shared__ float Wt[2][4096];
    __shared__ float xs[8 * 192];

    const int tid  = threadIdx.x;
    const int lane = tid & 63;
    const int wv   = tid >> 6;
    const int j    = lane & 31;
    const int kh   = lane >> 5;
    const int bg   = blockIdx.x / NSLICE_F;
    const int sl   = blockIdx.x % NSLICE_F;
    const int i0   = sl * I_TILE_F;
    const int b0   = bg * 8 + wv * 2;

    const float* wsrc[4];
    #pragma unroll
    for (int t = 0; t < 4; ++t) {
        const int q  = (wv * 4 + t) * 1024 + lane * 16;
        const int rr = q >> 8;
        const int cb = (q & 255) ^ ((rr & 15) << 4);
        const int js = rr & 31;
        const int c  = (rr >> 5) * 64 + (cb >> 2);
        wsrc[t] = W + (size_t)js * WJ + c;
    }

    auto stage = [&](int buf, int i) {
        #pragma unroll
        for (int t = 0; t < 4; ++t)
            __builtin_amdgcn_global_load_lds(
                (const __attribute__((address_space(1))) uint32_t*)
                    (wsrc[t] + (size_t)i * 128),
                (__attribute__((address_space(3))) uint32_t*)
                    &Wt[buf][(wv * 4 + t) * 256], 16, 0, 0);
    };

    stage(0, i0);

    for (int cf = tid; cf < 384; cf += 256) {
        const int bl = cf / 48;
        const int rm = cf - bl * 48;
        float4 v = *reinterpret_cast<const float4*>(
            x + ((size_t)(bg * 8 + bl) * 1152 + i0) * 8 + rm * 4);
        *reinterpret_cast<float4*>(xs + bl * 192 + rm * 4) = v;
    }

    float Vr[2][8];
    if (R > 0) {
        #pragma unroll
        for (int bb = 0; bb < 2; ++bb) {
            const float* vp = Vacc + ((size_t)(b0 + bb) * 32 + j) * 16 + kh * 8;
            const float4 va = *reinterpret_cast<const float4*>(vp);
            const float4 vb = *reinterpret_cast<const float4*>(vp + 4);
            Vr[bb][0] = va.x * 1.44269504f; Vr[bb][1] = va.y * 1.44269504f;
            Vr[bb][2] = va.z * 1.44269504f; Vr[bb][3] = va.w * 1.44269504f;
            Vr[bb][4] = vb.x * 1.44269504f; Vr[bb][5] = vb.y * 1.44269504f;
            Vr[bb][6] = vb.z * 1.44269504f; Vr[bb][7] = vb.w * 1.44269504f;
        }
    }

    float sacc[2][8];
    #pragma unroll
    for (int bb = 0; bb < 2; ++bb)
        #pragma unroll
        for (int kk = 0; kk < 8; ++kk) sacc[bb][kk] = 0.0f;

    __syncthreads();

    const int sw = (j & 15) << 4;

    for (int ii = 0; ii < I_TILE_F; ++ii) {
        const int cur = ii & 1;
        if (ii + 1 < I_TILE_F) stage(cur ^ 1, i0 + ii + 1);

        float4 xa[2], xb[2];
        #pragma unroll
        for (int bb = 0; bb < 2; ++bb) {
            const float* xp = xs + (wv * 2 + bb) * 192 + ii * 8;
            xa[bb] = *reinterpret_cast<const float4*>(xp);
            xb[bb] = *reinterpret_cast<const float4*>(xp + 4);
        }

        const char* lbase = reinterpret_cast<const char*>(&Wt[cur][0]) + lane * 256;

        float u[2][8];
        #pragma unroll
        for (int kk = 0; kk < 8; ++kk) {
            const float4 w0 = *reinterpret_cast<const float4*>(lbase + ((kk * 32) ^ sw));
            const float4 w1 = *reinterpret_cast<const float4*>(lbase + ((kk * 32 + 16) ^ sw));
            #pragma unroll
            for (int bb = 0; bb < 2; ++bb) {
                float acc;
                acc = w0.x * xa[bb].x;
                acc = fmaf(w0.y, xa[bb].y, acc);
                acc = fmaf(w0.z, xa[bb].z, acc);
                acc = fmaf(w0.w, xa[bb].w, acc);
                acc = fmaf(w1.x, xb[bb].x, acc);
                acc = fmaf(w1.y, xb[bb].y, acc);
                acc = fmaf(w1.z, xb[bb].z, acc);
                acc = fmaf(w1.w, xb[bb].w, acc);
                u[bb][kk] = acc;
            }
        }

        if (R == 0) {
            #pragma unroll
            for (int bb = 0; bb < 2; ++bb)
                #pragma unroll
                for (int kk = 0; kk < 8; ++kk)
                    sacc[bb][kk] = fmaf(0.03125f, u[bb][kk], sacc[bb][kk]);
        } else {
            float p0 = u[0][0] * Vr[0][0];
            float p1 = u[1][0] * Vr[1][0];
            #pragma unroll
            for (int kk = 1; kk < 8; ++kk) {
                p0 = fmaf(u[0][kk], Vr[0][kk], p0);
                p1 = fmaf(u[1][kk], Vr[1][kk], p1);
            }
            p0 += __shfl_xor(p0, 32);
            p1 += __shfl_xor(p1, 32);
            const float pq = kh ? p1 : p0;
            const float e  = exp2f(pq);
            float den = e;
            den += __shfl_xor(den, 1);
            den += __shfl_xor(den, 2);
            den += __shfl_xor(den, 4);
            den += __shfl_xor(den, 8);
            den += __shfl_xor(den, 16);
            const float cf_own = e * __builtin_amdgcn_rcpf(den);
            const float cf_oth = __shfl_xor(cf_own, 32);
            const float cf0 = kh ? cf_oth : cf_own;
            const float cf1 = kh ? cf_own : cf_oth;
            #pragma unroll
            for (int kk = 0; kk < 8; ++kk) {
                sacc[0][kk] = fmaf(cf0, u[0][kk], sacc[0][kk]);
                sacc[1][kk] = fmaf(cf1, u[1][kk], sacc[1][kk]);
            }
        }
        __syncthreads();
    }

    {
        float* ep = &Wt[0][0] + wv * 1024;
        #pragma unroll
        for (int bb = 0; bb < 2; ++bb)
            #pragma unroll
            for (int kk = 0; kk < 8; ++kk)
                ep[bb * 512 + j * 16 + ((kh * 8 + kk) ^ ((j >> 1) & 15))] =
                    sacc[bb][kk];

        float* sg = s + (size_t)b0 * 512;
        #pragma unroll
        for (int c = 0; c < 16; ++c) {
            const int m   = c * 64 + lane;
            const int bb2 = m >> 9;
            const int j2  = (m >> 4) & 31;
            const int k2  = m & 15;
            const float v = ep[bb2 * 512 + j2 * 16 + (k2 ^ ((j2 >> 1) & 15))];
            atomicAdd(&sg[m], v);
        }
    }
}

// Fallback squash. MODE 0: Vacc = v, zero s; 1: Vacc += v, zero s; 2: out = v
template<int MODE>
__global__ __launch_bounds__(256)
void caps_squash(float* __restrict__ s,
                 float* __restrict__ Vacc,
                 float* __restrict__ out)
{
    const int t = blockIdx.x * 256 + threadIdx.x;
    const float sv = s[t];
    float p = sv * sv;
    p += __shfl_xor(p, 1);
    p += __shfl_xor(p, 2);
    p += __shfl_xor(p, 4);
    p += __shfl_xor(p, 8);
    const float scale = p / ((1.0f + p) * sqrtf(p + 1e-7f));
    const float v = scale * sv;
    if (MODE == 0)      { Vacc[t] = v;  s[t] = 0.0f; }
    else if (MODE == 1) { Vacc[t] += v; s[t] = 0.0f; }
    else                { out[t] = v; }
}

extern "C" void kernel_launch(void* const* d_in, const int* in_sizes, int n_in,
                              void* d_out, int out_size, void* d_ws, size_t ws_size,
                              hipStream_t stream)
{
    const float* x = (const float*)d_in[0];   // [128,1152,8]
    const float* W = (const float*)d_in[1];   // [32,1152,16,8]
    float* out = (float*)d_out;               // [128,32,16]

    const size_t W3B = (size_t)589824 * 16;   // 9,437,184 B
    const size_t X2B = (size_t)147456 * 16;   // 2,359,296 B
    const size_t SB  = (size_t)65536 * sizeof(float);   // 256 KB

    if (ws_size >= W3B + X2B + 3 * SB) {
        ushort* W3 = (ushort*)d_ws;
        ushort* X2 = (ushort*)((char*)d_ws + W3B);
        float* s0  = (float*)((char*)d_ws + W3B + X2B);
        float* s1  = s0 + 65536;
        float* s2  = s1 + 65536;

        hipMemsetAsync(s0, 0, 3 * SB, stream);
        prep<<<2304, 256, 0, stream>>>(W, x, W3, X2);

        dim3 grid(512);    // 8 bgroups x 64 i-slices
        dim3 blk(512);
        caps_route0<<<grid, blk, 0, stream>>>(W3, X2, s0);
        caps_route_sm<1><<<grid, blk, 0, stream>>>(W3, X2, s0, s0, s1);
        caps_route_sm<2><<<grid, blk, 0, stream>>>(W3, X2, s0, s1, s2);
        caps_squash_out<<<256, 256, 0, stream>>>(s2, out);
    } else {
        float* Vacc = (float*)d_ws;
        float* sbuf = Vacc + 65536;
        hipMemsetAsync(sbuf, 0, SB, stream);

        dim3 grid(16 * NSLICE_F);  // 768 WGs
        dim3 blk(256);
        caps_route_f32<0><<<grid, blk, 0, stream>>>(x, W, Vacc, sbuf);
        caps_squash<0><<<256, 256, 0, stream>>>(sbuf, Vacc, out);
        caps_route_f32<1><<<grid, blk, 0, stream>>>(x, W, Vacc, sbuf);
        caps_squash<1><<<256, 256, 0, stream>>>(sbuf, Vacc, out);
        caps_route_f32<2><<<grid, blk, 0, stream>>>(x, W, Vacc, sbuf);
        caps_squash<2><<<256, 256, 0, stream>>>(sbuf, Vacc, out);
    }
}